// Round 3
// baseline (141.306 us; speedup 1.0000x reference)
//
#include <hip/hip_runtime.h>
#include <hip/hip_bf16.h>

// GAT layer: B=2, N=2048, C_IN=128, H=16, c=8.
// E(i,j) = exp(lrelu(lp_i+lc_j))*2^-12 = max(P1_i*Q1_j, P2_i*Q2_j)*adj  (f16).
// Aggregation: mfma_f32_16x16x32_f16; B-operand = [h feats | ones buffer].
// Round 17: kill attn's serial staging phase. Adjacency is no longer staged
// in LDS: every wave loads its own 32x32 sub-block per chunk straight from
// global (wave 0 misses to HBM, waves 1-7 hit L2), 1-chunk-ahead register
// double-buffer inside the MFMA loop -> adj read + adj_out copy-write overlap
// compute continuously (no barrier drains vmcnt). Wave 0 alone writes the
// fused adj copy. LDS = 32 KB sQ only.
// d_out = [out: B*N*128][adj copy: B*N*N]

#define B_   2
#define N_   2048
#define CIN_ 128
#define H_   16

typedef _Float16 h2  __attribute__((ext_vector_type(2)));
typedef _Float16 v8h __attribute__((ext_vector_type(8)));
typedef float    v4f __attribute__((ext_vector_type(4)));

#define SC6 0.015625f   // 2^-6

__device__ inline h2 pk_f16(float a, float b) {
  return __builtin_bit_cast(h2, __builtin_amdgcn_cvt_pkrtz(a, b));
}
__device__ inline unsigned as_u32(h2 v) { return __builtin_bit_cast(unsigned, v); }
__device__ inline h2 as_h2(unsigned u) { return __builtin_bit_cast(h2, u); }

__global__ __launch_bounds__(128) void proj_kernel(
    const float* __restrict__ nf, const float* __restrict__ W,
    const float* __restrict__ bias, const float* __restrict__ a,
    unsigned* __restrict__ hQ, unsigned* __restrict__ qI,
    float* __restrict__ lpT, unsigned* __restrict__ ones) {
  const int row0 = blockIdx.x * 4;       // 4 consecutive rows (same batch)
  const int t    = threadIdx.x;          // output column 0..127
  if (blockIdx.x == 0) {                 // ones-buffer for B-operand cols 8..15
    ones[t] = 0x3C003C00u; ones[t + 128] = 0x3C003C00u;
    ones[t + 256] = 0x3C003C00u; ones[t + 384] = 0x3C003C00u;
  }
  __shared__ float sNf[4][CIN_];
  ((float4*)&sNf[0][0])[t] = ((const float4*)(nf + (long)row0 * CIN_))[t];
  __syncthreads();
  float acc[4];
  const float bv = bias[t];
#pragma unroll
  for (int r = 0; r < 4; ++r) acc[r] = bv;
#pragma unroll 8
  for (int k = 0; k < CIN_; ++k) {
    const float w = W[k * 128 + t];
#pragma unroll
    for (int r = 0; r < 4; ++r) acc[r] = fmaf(sNf[r][k], w, acc[r]);
  }
  const int h = t >> 3, kc = t & 7;
  const int b = row0 >> 11, n0 = row0 & (N_ - 1);
  const int bh = b * H_ + h;
  const int cdw = n0 >> 1;               // j-pair dword index (2-aligned)
  uint2 hv;
  hv.x = as_u32(pk_f16(acc[0], acc[1]));
  hv.y = as_u32(pk_f16(acc[2], acc[3]));
  *(uint2*)(hQ + ((long)(bh * 8 + kc)) * (N_ / 2) + cdw) = hv;

  const float ap = a[h * 16 + kc], ac = a[h * 16 + 8 + kc];
  float lpv[4], lcv[4];
#pragma unroll
  for (int r = 0; r < 4; ++r) {
    float x = acc[r] * ap, y = acc[r] * ac;
#pragma unroll
    for (int s = 1; s < 8; s <<= 1) {
      x += __shfl_xor(x, s);
      y += __shfl_xor(y, s);
    }
    lpv[r] = x; lcv[r] = y;
  }
  if (kc == 0) {
    float4 l0 = {lpv[0], lpv[1], lpv[2], lpv[3]};
    *(float4*)(lpT + (long)bh * N_ + n0) = l0;
    uint2 q1, q2;
    q1.x = as_u32(pk_f16(__expf(lcv[0]) * SC6, __expf(lcv[1]) * SC6));
    q1.y = as_u32(pk_f16(__expf(lcv[2]) * SC6, __expf(lcv[3]) * SC6));
    q2.x = as_u32(pk_f16(__expf(0.2f * lcv[0]) * SC6, __expf(0.2f * lcv[1]) * SC6));
    q2.y = as_u32(pk_f16(__expf(0.2f * lcv[2]) * SC6, __expf(0.2f * lcv[3]) * SC6));
    // interleave: chunk(16 pairs)=32dw: [q1 quad0|q2 quad0|...|q1 quad3|q2 quad3]
    const int addr = bh * 2048 + (cdw >> 4) * 32 + ((cdw >> 2) & 3) * 8;
    const int off  = cdw & 3;            // 0 or 2
    *(uint2*)(qI + addr + off)     = q1;
    *(uint2*)(qI + addr + 4 + off) = q2;
  }
}

__global__ __launch_bounds__(512) void attn_kernel(
    const float* __restrict__ adj, const unsigned* __restrict__ hQ,
    const unsigned* __restrict__ qI, const float* __restrict__ lpT,
    const unsigned* __restrict__ ones, float* __restrict__ pA,
    float* __restrict__ pL, float* __restrict__ adj_out) {
  const int jq   = blockIdx.x & 3;       // j-quarter (512 wide)
  const int rest = blockIdx.x >> 2;
  const int b    = rest >> 6;            // 64 i-tiles (32-row) per batch
  const int i0   = (rest & 63) * 32;
  const int tid  = threadIdx.x;
  const int w    = tid >> 6;             // 0..7; wave = heads w and w+8
  const int lane = tid & 63;

  __shared__ unsigned sQ[8192];          // 32 KB: q1/q2 for 16 heads (qI layout)

  // ---- Stage sQ: thread t copies 16 dw of head (t>>5)'s j-quarter.
  {
    const int head = tid >> 5;
    const int off  = (tid & 31) * 16;
    const uint4* src = (const uint4*)(qI + (b * H_ + head) * 2048 + jq * 512 + off);
    uint4* dst = (uint4*)(sQ + head * 512 + off);
    dst[0] = src[0]; dst[1] = src[1]; dst[2] = src[2]; dst[3] = src[3];
  }

  const int m  = lane & 15;              // A row / B col / D col
  const int q  = lane >> 4;              // k-quad
  const int bh0 = b * H_ + w;            // head-group 0
  const int bh1 = bh0 + 8;               // head-group 1

  const float lpa0 = lpT[(long)bh0 * N_ + i0 + m];
  const float lpb0 = lpT[(long)bh0 * N_ + i0 + 16 + m];
  const float lpa1 = lpT[(long)bh1 * N_ + i0 + m];
  const float lpb1 = lpT[(long)bh1 * N_ + i0 + 16 + m];
  const h2 P1a0 = pk_f16(__expf(lpa0) * SC6, __expf(lpa0) * SC6);
  const h2 P2a0 = pk_f16(__expf(0.2f * lpa0) * SC6, __expf(0.2f * lpa0) * SC6);
  const h2 P1b0 = pk_f16(__expf(lpb0) * SC6, __expf(lpb0) * SC6);
  const h2 P2b0 = pk_f16(__expf(0.2f * lpb0) * SC6, __expf(0.2f * lpb0) * SC6);
  const h2 P1a1 = pk_f16(__expf(lpa1) * SC6, __expf(lpa1) * SC6);
  const h2 P2a1 = pk_f16(__expf(0.2f * lpa1) * SC6, __expf(0.2f * lpa1) * SC6);
  const h2 P1b1 = pk_f16(__expf(lpb1) * SC6, __expf(lpb1) * SC6);
  const h2 P2b1 = pk_f16(__expf(0.2f * lpb1) * SC6, __expf(0.2f * lpb1) * SC6);

  // per-lane adjacency row pointers (subtile 0 row m, subtile 1 row m+16;
  // col slice q*8 .. q*8+7 within each 32-col chunk)
  const long rbase0 = (long)(b * N_ + i0 + m) * N_ + jq * 512 + q * 8;
  const long rbase1 = rbase0 + 16L * N_;
  const float* aR0 = adj + rbase0;
  const float* aR1 = adj + rbase1;
  float* oR0 = adj_out + rbase0;
  float* oR1 = adj_out + rbase1;

  const unsigned* sq0 = sQ + w * 512 + q * 8;
  const unsigned* sq1 = sQ + (w + 8) * 512 + q * 8;
  const unsigned* hp0 = (m < 8)
      ? hQ + ((long)(bh0 * 8 + m)) * (N_ / 2) + jq * 256 + q * 4
      : ones + q * 4;
  const unsigned* hp1 = (m < 8)
      ? hQ + ((long)(bh1 * 8 + m)) * (N_ / 2) + jq * 256 + q * 4
      : ones + q * 4;

  v4f acc0a = {0.f, 0.f, 0.f, 0.f}, acc1a = {0.f, 0.f, 0.f, 0.f};
  v4f acc0b = {0.f, 0.f, 0.f, 0.f}, acc1b = {0.f, 0.f, 0.f, 0.f};

  // prologue: adjacency chunk 0 + hQ chunks 0/1 in flight
  float4 A0[2], Bb0[2], A1[2], Bb1[2];
  A0[0]  = *(const float4*)(aR0);
  Bb0[0] = *(const float4*)(aR0 + 4);
  A1[0]  = *(const float4*)(aR1);
  Bb1[0] = *(const float4*)(aR1 + 4);
  uint4 h0[2], h1[2];
  h0[0] = *(const uint4*)(hp0);      h1[0] = *(const uint4*)(hp1);
  h0[1] = *(const uint4*)(hp0 + 16); h1[1] = *(const uint4*)(hp1 + 16);

  __syncthreads();                       // sQ ready

#pragma unroll
  for (int ch = 0; ch < 16; ++ch) {
    const int p  = ch & 1;
    const int nn = (ch + 1) & 1;
    const int nco = ((ch + 1) & 15) * 32;   // wraps to 0 at ch=15 (harmless)
    // issue next chunk's adjacency loads (overlap with this chunk's compute)
    A0[nn]  = *(const float4*)(aR0 + nco);
    Bb0[nn] = *(const float4*)(aR0 + nco + 4);
    A1[nn]  = *(const float4*)(aR1 + nco);
    Bb1[nn] = *(const float4*)(aR1 + nco + 4);
    // hQ prefetch for ch+2
    const int pf = ((ch + 2) & 15) * 16;
    const uint4 nh0 = *(const uint4*)(hp0 + pf);
    const uint4 nh1 = *(const uint4*)(hp1 + pf);

    // fused adjacency copy: one wave writes (all waves hold identical data)
    if (w == 0) {
      *(float4*)(oR0 + ch * 32)     = A0[p];
      *(float4*)(oR0 + ch * 32 + 4) = Bb0[p];
      *(float4*)(oR1 + ch * 32)     = A1[p];
      *(float4*)(oR1 + ch * 32 + 4) = Bb1[p];
    }

    // adjacency -> f16 (values are exactly 0.0/1.0)
    uint4 Av0, Av1;
    Av0.x = as_u32(pk_f16(A0[p].x,  A0[p].y));  Av0.y = as_u32(pk_f16(A0[p].z,  A0[p].w));
    Av0.z = as_u32(pk_f16(Bb0[p].x, Bb0[p].y)); Av0.w = as_u32(pk_f16(Bb0[p].z, Bb0[p].w));
    Av1.x = as_u32(pk_f16(A1[p].x,  A1[p].y));  Av1.y = as_u32(pk_f16(A1[p].z,  A1[p].w));
    Av1.z = as_u32(pk_f16(Bb1[p].x, Bb1[p].y)); Av1.w = as_u32(pk_f16(Bb1[p].z, Bb1[p].w));

    const uint4 q1c0 = *(const uint4*)(sq0 + ch * 32);
    const uint4 q2c0 = *(const uint4*)(sq0 + ch * 32 + 4);
    const uint4 q1c1 = *(const uint4*)(sq1 + ch * 32);
    const uint4 q2c1 = *(const uint4*)(sq1 + ch * 32 + 4);

    // head-group 0
    {
      const h2 Q1x = as_h2(q1c0.x), Q1y = as_h2(q1c0.y), Q1z = as_h2(q1c0.z), Q1w = as_h2(q1c0.w);
      const h2 Q2x = as_h2(q2c0.x), Q2y = as_h2(q2c0.y), Q2z = as_h2(q2c0.z), Q2w = as_h2(q2c0.w);
      const v8h bf = __builtin_bit_cast(v8h, h0[p]);
      const uint4 af0 = {
        as_u32(__builtin_elementwise_max(P1a0 * Q1x, P2a0 * Q2x) * as_h2(Av0.x)),
        as_u32(__builtin_elementwise_max(P1a0 * Q1y, P2a0 * Q2y) * as_h2(Av0.y)),
        as_u32(__builtin_elementwise_max(P1a0 * Q1z, P2a0 * Q2z) * as_h2(Av0.z)),
        as_u32(__builtin_elementwise_max(P1a0 * Q1w, P2a0 * Q2w) * as_h2(Av0.w))};
      acc0a = __builtin_amdgcn_mfma_f32_16x16x32_f16(
          __builtin_bit_cast(v8h, af0), bf, acc0a, 0, 0, 0);
      const uint4 af1 = {
        as_u32(__builtin_elementwise_max(P1b0 * Q1x, P2b0 * Q2x) * as_h2(Av1.x)),
        as_u32(__builtin_elementwise_max(P1b0 * Q1y, P2b0 * Q2y) * as_h2(Av1.y)),
        as_u32(__builtin_elementwise_max(P1b0 * Q1z, P2b0 * Q2z) * as_h2(Av1.z)),
        as_u32(__builtin_elementwise_max(P1b0 * Q1w, P2b0 * Q2w) * as_h2(Av1.w))};
      acc1a = __builtin_amdgcn_mfma_f32_16x16x32_f16(
          __builtin_bit_cast(v8h, af1), bf, acc1a, 0, 0, 0);
    }
    // head-group 1
    {
      const h2 Q1x = as_h2(q1c1.x), Q1y = as_h2(q1c1.y), Q1z = as_h2(q1c1.z), Q1w = as_h2(q1c1.w);
      const h2 Q2x = as_h2(q2c1.x), Q2y = as_h2(q2c1.y), Q2z = as_h2(q2c1.z), Q2w = as_h2(q2c1.w);
      const v8h bf = __builtin_bit_cast(v8h, h1[p]);
      const uint4 af0 = {
        as_u32(__builtin_elementwise_max(P1a1 * Q1x, P2a1 * Q2x) * as_h2(Av0.x)),
        as_u32(__builtin_elementwise_max(P1a1 * Q1y, P2a1 * Q2y) * as_h2(Av0.y)),
        as_u32(__builtin_elementwise_max(P1a1 * Q1z, P2a1 * Q2z) * as_h2(Av0.z)),
        as_u32(__builtin_elementwise_max(P1a1 * Q1w, P2a1 * Q2w) * as_h2(Av0.w))};
      acc0b = __builtin_amdgcn_mfma_f32_16x16x32_f16(
          __builtin_bit_cast(v8h, af0), bf, acc0b, 0, 0, 0);
      const uint4 af1 = {
        as_u32(__builtin_elementwise_max(P1b1 * Q1x, P2b1 * Q2x) * as_h2(Av1.x)),
        as_u32(__builtin_elementwise_max(P1b1 * Q1y, P2b1 * Q2y) * as_h2(Av1.y)),
        as_u32(__builtin_elementwise_max(P1b1 * Q1z, P2b1 * Q2z) * as_h2(Av1.z)),
        as_u32(__builtin_elementwise_max(P1b1 * Q1w, P2b1 * Q2w) * as_h2(Av1.w))};
      acc1b = __builtin_amdgcn_mfma_f32_16x16x32_f16(
          __builtin_bit_cast(v8h, af1), bf, acc1b, 0, 0, 0);
    }
    // rotate hQ double-buffer (nh = data for ch+2)
    h0[p] = nh0; h1[p] = nh1;
  }

  // D: col = lane&15, row = q*4 + reg. Write partials (no division).
#pragma unroll
  for (int g = 0; g < 2; ++g) {          // head-group
    const int hw = g * 8 + w;
#pragma unroll
    for (int u = 0; u < 2; ++u) {        // i-subtile
      const v4f av = g ? (u ? acc1b : acc0b) : (u ? acc1a : acc0a);
#pragma unroll
      for (int r = 0; r < 4; ++r) {
        const int gidx = (b * N_ + i0 + u * 16 + q * 4 + r) * H_ + hw;
        if (m < 8)  pA[jq * 524288 + (long)gidx * 8 + m] = av[r];
        if (m == 8) pL[jq * 65536 + gidx] = av[r];
      }
    }
  }
}

__global__ __launch_bounds__(512) void combine_kernel(
    const float* __restrict__ pA, const float* __restrict__ pL,
    float* __restrict__ out) {
  const int g = blockIdx.x * 512 + threadIdx.x;    // = ((b*N+i)*16+h)*8+k
  const int gl = g >> 3;
  const float s = pL[gl] + pL[gl + 65536] + pL[gl + 131072] + pL[gl + 196608];
  const float v = pA[g] + pA[g + 524288] + pA[g + 1048576] + pA[g + 1572864];
  out[g] = v / s;
}

extern "C" void kernel_launch(void* const* d_in, const int* in_sizes, int n_in,
                              void* d_out, int out_size, void* d_ws, size_t ws_size,
                              hipStream_t stream) {
  const float* nf   = (const float*)d_in[0];
  const float* adj  = (const float*)d_in[1];
  const float* W    = (const float*)d_in[2];
  const float* bias = (const float*)d_in[3];
  const float* a    = (const float*)d_in[4];

  float* out     = (float*)d_out;
  float* adj_out = out + (long)B_ * N_ * H_ * 8;    // 524288 offset

  unsigned* ws   = (unsigned*)d_ws;
  unsigned* hQ   = ws;                       // 262144 dw
  unsigned* qI   = ws + 262144;              // 65536 dw
  float*    lpT  = (float*)(ws + 327680);    // 65536 floats
  unsigned* ones = ws + 393216;              // 512 dw
  float*    pA   = (float*)(ws + 393728);    // 4 * 524288 floats
  float*    pL   = (float*)(ws + 2490880);   // 4 * 65536 floats

  hipLaunchKernelGGL(proj_kernel, dim3(B_ * N_ / 4), dim3(128), 0, stream,
                     nf, W, bias, a, hQ, qI, lpT, ones);
  hipLaunchKernelGGL(attn_kernel, dim3(B_ * (N_ / 32) * 4), dim3(512), 0,
                     stream, adj, hQ, qI, lpT, ones, pA, pL, adj_out);
  hipLaunchKernelGGL(combine_kernel, dim3(1024), dim3(512), 0, stream,
                     pA, pL, out);
}

// Round 4
// 139.485 us; speedup vs baseline: 1.0131x; 1.0131x over previous
//
#include <hip/hip_runtime.h>
#include <hip/hip_bf16.h>

// GAT layer: B=2, N=2048, C_IN=128, H=16, c=8.
// E(i,j) = exp(lrelu(lp_i+lc_j))*2^-12 = max(P1_i*Q1_j, P2_i*Q2_j) & adjmask (f16).
// Aggregation: mfma_f32_16x16x32_f16; B-operand = [h feats | ones buffer].
// Round 18: full-j attention. Wave = 1 head x 32 i-rows x j=0..2047; softmax
// denominator comes out of the ones-column -> divide in-register, write out
// directly. pA/pL partials + combine kernel eliminated. Adjacency byte-masks
// (bit-exact E&mask, r15/r16-proven) staged in ONE 64KB LDS buffer in 4
// pipelined steps: step s+1 global loads issue BEFORE compute of step s
// (T14 split), convert+ds_write+barrier after -> HBM latency hides under
// 16 chunks of compute. adj_out copy spread across head-groups (hg copies
// step hg). Q/hQ streams read from global (L2-hot, broadcast-coalesced,
// 2-deep prefetch). Block 256 thr = 4 waves = 4 heads; grid 512 = 2 blk/CU.
// d_out = [out: B*N*128][adj copy: B*N*N]

#define B_   2
#define N_   2048
#define CIN_ 128
#define H_   16

typedef _Float16 h2  __attribute__((ext_vector_type(2)));
typedef _Float16 v8h __attribute__((ext_vector_type(8)));
typedef float    v4f __attribute__((ext_vector_type(4)));

#define SC6 0.015625f   // 2^-6

__device__ inline h2 pk_f16(float a, float b) {
  return __builtin_bit_cast(h2, __builtin_amdgcn_cvt_pkrtz(a, b));
}
__device__ inline unsigned as_u32(h2 v) { return __builtin_bit_cast(unsigned, v); }
__device__ inline h2 as_h2(unsigned u) { return __builtin_bit_cast(h2, u); }

// 4 adjacency floats (exactly 0.0/1.0) -> 4 mask bytes 0x00/0xFF, j0 in byte0.
__device__ inline unsigned mask4(float4 f) {
  unsigned r = (unsigned)f.x | ((unsigned)f.y << 8) |
               ((unsigned)f.z << 16) | ((unsigned)f.w << 24);
  return (r << 8) - r;   // per-byte 0x01 -> 0xFF
}

__global__ __launch_bounds__(128) void proj_kernel(
    const float* __restrict__ nf, const float* __restrict__ W,
    const float* __restrict__ bias, const float* __restrict__ a,
    unsigned* __restrict__ hQ, unsigned* __restrict__ qI,
    float* __restrict__ lpT, unsigned* __restrict__ ones) {
  const int row0 = blockIdx.x * 4;       // 4 consecutive rows (same batch)
  const int t    = threadIdx.x;          // output column 0..127
  if (blockIdx.x == 0) {                 // ones-buffer for B-operand cols 8..15
    ones[t] = 0x3C003C00u; ones[t + 128] = 0x3C003C00u;
    ones[t + 256] = 0x3C003C00u; ones[t + 384] = 0x3C003C00u;
  }
  __shared__ float sNf[4][CIN_];
  ((float4*)&sNf[0][0])[t] = ((const float4*)(nf + (long)row0 * CIN_))[t];
  __syncthreads();
  float acc[4];
  const float bv = bias[t];
#pragma unroll
  for (int r = 0; r < 4; ++r) acc[r] = bv;
#pragma unroll 8
  for (int k = 0; k < CIN_; ++k) {
    const float w = W[k * 128 + t];
#pragma unroll
    for (int r = 0; r < 4; ++r) acc[r] = fmaf(sNf[r][k], w, acc[r]);
  }
  const int h = t >> 3, kc = t & 7;
  const int b = row0 >> 11, n0 = row0 & (N_ - 1);
  const int bh = b * H_ + h;
  const int cdw = n0 >> 1;               // j-pair dword index (2-aligned)
  uint2 hv;
  hv.x = as_u32(pk_f16(acc[0], acc[1]));
  hv.y = as_u32(pk_f16(acc[2], acc[3]));
  *(uint2*)(hQ + ((long)(bh * 8 + kc)) * (N_ / 2) + cdw) = hv;

  const float ap = a[h * 16 + kc], ac = a[h * 16 + 8 + kc];
  float lpv[4], lcv[4];
#pragma unroll
  for (int r = 0; r < 4; ++r) {
    float x = acc[r] * ap, y = acc[r] * ac;
#pragma unroll
    for (int s = 1; s < 8; s <<= 1) {
      x += __shfl_xor(x, s);
      y += __shfl_xor(y, s);
    }
    lpv[r] = x; lcv[r] = y;
  }
  if (kc == 0) {
    float4 l0 = {lpv[0], lpv[1], lpv[2], lpv[3]};
    *(float4*)(lpT + (long)bh * N_ + n0) = l0;
    uint2 q1, q2;
    q1.x = as_u32(pk_f16(__expf(lcv[0]) * SC6, __expf(lcv[1]) * SC6));
    q1.y = as_u32(pk_f16(__expf(lcv[2]) * SC6, __expf(lcv[3]) * SC6));
    q2.x = as_u32(pk_f16(__expf(0.2f * lcv[0]) * SC6, __expf(0.2f * lcv[1]) * SC6));
    q2.y = as_u32(pk_f16(__expf(0.2f * lcv[2]) * SC6, __expf(0.2f * lcv[3]) * SC6));
    // interleave: chunk(16 pairs)=32dw: [q1 quad0|q2 quad0|...|q1 quad3|q2 quad3]
    const int addr = bh * 2048 + (cdw >> 4) * 32 + ((cdw >> 2) & 3) * 8;
    const int off  = cdw & 3;            // 0 or 2
    *(uint2*)(qI + addr + off)     = q1;
    *(uint2*)(qI + addr + 4 + off) = q2;
  }
}

__global__ __launch_bounds__(256) void attn_kernel(
    const float* __restrict__ adj, const unsigned* __restrict__ hQ,
    const unsigned* __restrict__ qI, const float* __restrict__ lpT,
    const unsigned* __restrict__ ones, float* __restrict__ out,
    float* __restrict__ adj_out) {
  const int hg   = blockIdx.x & 3;       // head-group (4 heads each)
  const int it   = (blockIdx.x >> 2) & 63;
  const int b    = blockIdx.x >> 8;
  const int i0   = it * 32;
  const int t    = threadIdx.x;          // 0..255
  const int w    = t >> 6;               // wave 0..3
  const int lane = t & 63;
  const int m    = lane & 15;            // A row / B col / D col
  const int q    = lane >> 4;            // k-quad
  const int h    = hg * 4 + w;           // this wave's head
  const int bh   = b * H_ + h;

  // masks: idx = u*4096 + ch*64 + q*16 + m  (uint2 = 8 cols), 64 KB total
  __shared__ uint2 sAm[8192];

  const int  tm = t & 15, tq = t >> 4;   // staging decomposition
  const long abase = ((long)(b * N_) + i0) * N_;

  float4 fa[2][4], fb[2][4];
  auto STAGE_LOAD = [&](int ss) {
#pragma unroll
    for (int u = 0; u < 2; ++u)
#pragma unroll
      for (int k = 0; k < 4; ++k) {
        const int qc  = ss * 64 + k * 16 + tq;
        const int col = qc * 8;          // = (qc>>2)*32 + (qc&3)*8
        const float* ap = adj + abase + (long)(u * 16 + tm) * N_ + col;
        fa[u][k] = *(const float4*)(ap);
        fb[u][k] = *(const float4*)(ap + 4);
      }
  };
  auto STAGE_WRITE = [&](int ss) {
    const bool docopy = (ss == hg);      // spread adj copy across head-groups
#pragma unroll
    for (int u = 0; u < 2; ++u)
#pragma unroll
      for (int k = 0; k < 4; ++k) {
        uint2 mv;
        mv.x = mask4(fa[u][k]); mv.y = mask4(fb[u][k]);
        sAm[u * 4096 + ss * 1024 + k * 256 + t] = mv;
        if (docopy) {
          const int qc  = ss * 64 + k * 16 + tq;
          const int col = qc * 8;
          float* op = adj_out + abase + (long)(u * 16 + tm) * N_ + col;
          *(float4*)(op)     = fa[u][k];
          *(float4*)(op + 4) = fb[u][k];
        }
      }
  };

  // per-row parent factors (subtile 0: rows i0+m, subtile 1: rows i0+16+m)
  const float lpa = lpT[(long)bh * N_ + i0 + m];
  const float lpb = lpT[(long)bh * N_ + i0 + 16 + m];
  const float e1a = __expf(lpa) * SC6, e2a = __expf(0.2f * lpa) * SC6;
  const float e1b = __expf(lpb) * SC6, e2b = __expf(0.2f * lpb) * SC6;
  const h2 P1a = pk_f16(e1a, e1a), P2a = pk_f16(e2a, e2a);
  const h2 P1b = pk_f16(e1b, e1b), P2b = pk_f16(e2b, e2b);

  // global Q/hQ streams (L2-hot), 2-deep prefetch
  const unsigned* qp = qI + bh * 2048 + q * 8;
  const unsigned hmask = (m < 8) ? ~0u : 0u;
  const unsigned* hp = (m < 8)
      ? hQ + ((long)(bh * 8 + m)) * (N_ / 2) + q * 4
      : ones + q * 4;

  uint4 bq1[2], bq2[2], bhq[2];
  bq1[0] = *(const uint4*)(qp);       bq2[0] = *(const uint4*)(qp + 4);
  bq1[1] = *(const uint4*)(qp + 32);  bq2[1] = *(const uint4*)(qp + 36);
  bhq[0] = *(const uint4*)(hp);
  bhq[1] = *(const uint4*)(hp + (16 & hmask));

  v4f acc0 = {0.f, 0.f, 0.f, 0.f};       // rows i0 .. i0+15
  v4f acc1 = {0.f, 0.f, 0.f, 0.f};       // rows i0+16 .. i0+31

  // prologue: stage step 0
  STAGE_LOAD(0);
  STAGE_WRITE(0);
  __syncthreads();

  for (int s = 0; s < 4; ++s) {
    if (s < 3) STAGE_LOAD(s + 1);        // issue early; consumed after compute
#pragma unroll
    for (int cc = 0; cc < 16; ++cc) {
      const int ch = s * 16 + cc;
      const int p  = ch & 1;
      // prefetch ch+2 (overrun reads land in ws, discarded)
      const uint4 nq1 = *(const uint4*)(qp + (ch + 2) * 32);
      const uint4 nq2 = *(const uint4*)(qp + (ch + 2) * 32 + 4);
      const uint4 nhq = *(const uint4*)(hp + (((ch + 2) * 16) & hmask));

      const uint2 Mv0 = sAm[ch * 64 + lane];
      const uint2 Mv1 = sAm[4096 + ch * 64 + lane];
      const unsigned m0a = __builtin_amdgcn_perm(Mv0.x, Mv0.x, 0x01010000u);
      const unsigned m0b = __builtin_amdgcn_perm(Mv0.x, Mv0.x, 0x03030202u);
      const unsigned m0c = __builtin_amdgcn_perm(Mv0.y, Mv0.y, 0x01010000u);
      const unsigned m0d = __builtin_amdgcn_perm(Mv0.y, Mv0.y, 0x03030202u);
      const unsigned m1a = __builtin_amdgcn_perm(Mv1.x, Mv1.x, 0x01010000u);
      const unsigned m1b = __builtin_amdgcn_perm(Mv1.x, Mv1.x, 0x03030202u);
      const unsigned m1c = __builtin_amdgcn_perm(Mv1.y, Mv1.y, 0x01010000u);
      const unsigned m1d = __builtin_amdgcn_perm(Mv1.y, Mv1.y, 0x03030202u);

      const uint4 q1 = bq1[p], q2 = bq2[p];
      const h2 Q1x = as_h2(q1.x), Q1y = as_h2(q1.y), Q1z = as_h2(q1.z), Q1w = as_h2(q1.w);
      const h2 Q2x = as_h2(q2.x), Q2y = as_h2(q2.y), Q2z = as_h2(q2.z), Q2w = as_h2(q2.w);
      const v8h bf = __builtin_bit_cast(v8h, bhq[p]);

      const uint4 af0 = {
        as_u32(__builtin_elementwise_max(P1a * Q1x, P2a * Q2x)) & m0a,
        as_u32(__builtin_elementwise_max(P1a * Q1y, P2a * Q2y)) & m0b,
        as_u32(__builtin_elementwise_max(P1a * Q1z, P2a * Q2z)) & m0c,
        as_u32(__builtin_elementwise_max(P1a * Q1w, P2a * Q2w)) & m0d};
      acc0 = __builtin_amdgcn_mfma_f32_16x16x32_f16(
          __builtin_bit_cast(v8h, af0), bf, acc0, 0, 0, 0);
      const uint4 af1 = {
        as_u32(__builtin_elementwise_max(P1b * Q1x, P2b * Q2x)) & m1a,
        as_u32(__builtin_elementwise_max(P1b * Q1y, P2b * Q2y)) & m1b,
        as_u32(__builtin_elementwise_max(P1b * Q1z, P2b * Q2z)) & m1c,
        as_u32(__builtin_elementwise_max(P1b * Q1w, P2b * Q2w)) & m1d};
      acc1 = __builtin_amdgcn_mfma_f32_16x16x32_f16(
          __builtin_bit_cast(v8h, af1), bf, acc1, 0, 0, 0);

      bq1[p] = nq1; bq2[p] = nq2; bhq[p] = nhq;
    }
    if (s < 3) { STAGE_WRITE(s + 1); __syncthreads(); }
  }

  // D: col = m, row = q*4 + r (i-row offset). Denominator in col 8.
#pragma unroll
  for (int u = 0; u < 2; ++u) {
    const v4f av = u ? acc1 : acc0;
#pragma unroll
    for (int r = 0; r < 4; ++r) {
      const float sden = __shfl(av[r], (lane & 48) | 8);
      if (m < 8) {
        const long gi = ((long)(b * N_ + i0 + u * 16 + q * 4 + r)) * H_ + h;
        out[gi * 8 + m] = av[r] / sden;
      }
    }
  }
}

extern "C" void kernel_launch(void* const* d_in, const int* in_sizes, int n_in,
                              void* d_out, int out_size, void* d_ws, size_t ws_size,
                              hipStream_t stream) {
  const float* nf   = (const float*)d_in[0];
  const float* adj  = (const float*)d_in[1];
  const float* W    = (const float*)d_in[2];
  const float* bias = (const float*)d_in[3];
  const float* a    = (const float*)d_in[4];

  float* out     = (float*)d_out;
  float* adj_out = out + (long)B_ * N_ * H_ * 8;    // 524288 offset

  unsigned* ws   = (unsigned*)d_ws;
  unsigned* hQ   = ws;                       // 262144 dw
  unsigned* qI   = ws + 262144;              // 65536 dw
  float*    lpT  = (float*)(ws + 327680);    // 65536 floats
  unsigned* ones = ws + 393216;              // 512 dw

  hipLaunchKernelGGL(proj_kernel, dim3(B_ * N_ / 4), dim3(128), 0, stream,
                     nf, W, bias, a, hQ, qI, lpT, ones);
  hipLaunchKernelGGL(attn_kernel, dim3(B_ * 64 * 4), dim3(256), 0,
                     stream, adj, hQ, qI, lpT, ones, out, adj_out);
}